// Round 2
// baseline (144.215 us; speedup 1.0000x reference)
//
#include <hip/hip_runtime.h>

// ChamferDistance2D: B=8, N=M=8192, fp32, scalar output.
// cost = sum_b [ mean_i min_j d(i,j) + mean_j min_i d(i,j) ],  d = squared L2.
// d(i,j) = |p1_i|^2 + (|p2_j|^2 - 2 p1_i . p2_j); store min_j of the paren term.
//
// R2: packed fp32 (v_pk_fma_f32, VOP3P) — 2 FMA/lane/instr; this is the only
// path to MI355X's 157.3 TF fp32. Points packed in pairs across k; the LDS
// operand (qx,qy,qsq) is broadcast into both halves via op_sel (no extra regs).
// Per 4 pairs: 4 pk_fma + 2 v_min3_f32 = 1.5 instr/pair (was 2.5).
// IPT=32 so each broadcast ds_read_b128 feeds 32 pairs: LDS ~10us < VALU ~20.5us.
// S j-splits for occupancy (S=64 -> 1024 blocks = 16 waves/CU), partial mins
// (exact fp32, no atomics) to d_ws; S gated on ws_size (8MB proven, 32MB wanted).

#define BATCH 8
#define NPTS  8192
#define TPB   256
#define IPT   32
#define HIPT  (IPT / 2)

// d.lo = a.lo*b.lo + c.lo ; d.hi = a.hi*b.lo + c.lo   (src1,src2 broadcast lo)
__device__ inline float2 pk_fma_blo(float2 a, float2 b, float2 c) {
    float2 d;
    asm("v_pk_fma_f32 %0, %1, %2, %3 op_sel:[0,0,0] op_sel_hi:[1,0,0]"
        : "=v"(d) : "v"(a), "v"(b), "v"(c));
    return d;
}
// d.lo = a.lo*b.hi + c.lo ; d.hi = a.hi*b.hi + c.hi   (src1 broadcast hi)
__device__ inline float2 pk_fma_bhi(float2 a, float2 b, float2 c) {
    float2 d;
    asm("v_pk_fma_f32 %0, %1, %2, %3 op_sel:[0,1,0] op_sel_hi:[1,1,1]"
        : "=v"(d) : "v"(a), "v"(b), "v"(c));
    return d;
}
__device__ inline float min3f(float a, float b, float c) {
    float d;
    asm("v_min3_f32 %0, %1, %2, %3" : "=v"(d) : "v"(a), "v"(b), "v"(c));
    return d;
}

// grid.x = 2 * BATCH * S
template <int S>
__global__ __launch_bounds__(TPB, 4)
void chamfer_partial(const float* __restrict__ p1, const float* __restrict__ p2,
                     float* __restrict__ partial /* [2][B][S][N] */) {
    constexpr int JCH = NPTS / S;
    __shared__ float4 q[JCH];  // (x, y, |p|^2, pad)

    int blk   = blockIdx.x;
    int split = blk % S;
    int rest  = blk / S;
    int b     = rest & (BATCH - 1);
    int dir   = rest >> 3;

    const float2* a  = (const float2*)(dir ? p2 : p1) + (size_t)b * NPTS;
    const float2* bp = (const float2*)(dir ? p1 : p2) + (size_t)b * NPTS + split * JCH;

    int t = threadIdx.x;

    for (int j = t; j < JCH; j += TPB) {
        float2 v = bp[j];
        q[j] = make_float4(v.x, v.y, fmaf(v.x, v.x, v.y * v.y), 0.0f);
    }

    // my 32 points, packed in pairs: xp2[kk] = (-2x of pt 2kk, -2x of pt 2kk+1)
    float2 xp[HIPT], yp[HIPT];
    float  m[IPT];
#pragma unroll
    for (int kk = 0; kk < HIPT; ++kk) {
        float2 v0 = a[(2 * kk) * TPB + t];
        float2 v1 = a[(2 * kk + 1) * TPB + t];
        xp[kk] = make_float2(-2.0f * v0.x, -2.0f * v1.x);
        yp[kk] = make_float2(-2.0f * v0.y, -2.0f * v1.y);
        m[2 * kk] = 3.0e38f;
        m[2 * kk + 1] = 3.0e38f;
    }

    __syncthreads();

    for (int j = 0; j < JCH; j += 2) {
        float4 Q0 = q[j];
        float4 Q1 = q[j + 1];
        float2 q0xy = make_float2(Q0.x, Q0.y), q0zw = make_float2(Q0.z, Q0.w);
        float2 q1xy = make_float2(Q1.x, Q1.y), q1zw = make_float2(Q1.z, Q1.w);
#pragma unroll
        for (int kk = 0; kk < HIPT; ++kk) {
            float2 u0 = pk_fma_blo(xp[kk], q0xy, q0zw);   // xp*qx + qsq (both halves)
            float2 t0 = pk_fma_bhi(yp[kk], q0xy, u0);     // + yp*qy
            float2 u1 = pk_fma_blo(xp[kk], q1xy, q1zw);
            float2 t1 = pk_fma_bhi(yp[kk], q1xy, u1);
            m[2 * kk]     = min3f(m[2 * kk],     t0.x, t1.x);
            m[2 * kk + 1] = min3f(m[2 * kk + 1], t0.y, t1.y);
        }
    }

    float* outp = partial + ((size_t)((dir * BATCH + b) * S + split)) * NPTS;
#pragma unroll
    for (int k = 0; k < IPT; ++k)
        outp[k * TPB + t] = m[k];
}

// grid.x = 2 * BATCH * NPTS / TPB = 512
template <int S>
__global__ __launch_bounds__(TPB)
void chamfer_reduce(const float* __restrict__ p1, const float* __restrict__ p2,
                    const float* __restrict__ partial, float* __restrict__ out) {
    int gid   = blockIdx.x * TPB + threadIdx.x;
    int point = gid & (NPTS - 1);
    int rest  = gid >> 13;
    int b     = rest & (BATCH - 1);
    int dir   = rest >> 3;

    const float* base = partial + ((size_t)(dir * BATCH + b) * S) * NPTS + point;
    float m = base[0];
#pragma unroll
    for (int s = 1; s < S; ++s)
        m = fminf(m, base[(size_t)s * NPTS]);

    float2 v = ((const float2*)(dir ? p2 : p1))[(size_t)b * NPTS + point];
    float d = m + fmaf(v.x, v.x, v.y * v.y);

#pragma unroll
    for (int off = 32; off > 0; off >>= 1)
        d += __shfl_down(d, off, 64);

    __shared__ float wsum[TPB / 64];
    int lane = threadIdx.x & 63;
    int w    = threadIdx.x >> 6;
    if (lane == 0) wsum[w] = d;
    __syncthreads();
    if (threadIdx.x == 0) {
        float ssum = wsum[0] + wsum[1] + wsum[2] + wsum[3];
        atomicAdd(out, ssum * (1.0f / NPTS));
    }
}

extern "C" void kernel_launch(void* const* d_in, const int* in_sizes, int n_in,
                              void* d_out, int out_size, void* d_ws, size_t ws_size,
                              hipStream_t stream) {
    const float* p1 = (const float*)d_in[0];
    const float* p2 = (const float*)d_in[1];
    float* out      = (float*)d_out;
    float* partial  = (float*)d_ws;

    hipMemsetAsync(d_out, 0, sizeof(float), stream);

    auto need = [](int S) { return (size_t)2 * BATCH * S * NPTS * sizeof(float); };

    if (ws_size >= need(64)) {
        chamfer_partial<64><<<2 * BATCH * 64, TPB, 0, stream>>>(p1, p2, partial);
        chamfer_reduce<64><<<2 * BATCH * NPTS / TPB, TPB, 0, stream>>>(p1, p2, partial, out);
    } else if (ws_size >= need(32)) {
        chamfer_partial<32><<<2 * BATCH * 32, TPB, 0, stream>>>(p1, p2, partial);
        chamfer_reduce<32><<<2 * BATCH * NPTS / TPB, TPB, 0, stream>>>(p1, p2, partial, out);
    } else {
        chamfer_partial<16><<<2 * BATCH * 16, TPB, 0, stream>>>(p1, p2, partial);
        chamfer_reduce<16><<<2 * BATCH * NPTS / TPB, TPB, 0, stream>>>(p1, p2, partial, out);
    }
}

// Round 3
// 125.050 us; speedup vs baseline: 1.1533x; 1.1533x over previous
//
#include <hip/hip_runtime.h>

// ChamferDistance2D: B=8, N=M=8192, fp32, scalar output.
// cost = sum_b [ mean_i min_j d(i,j) + mean_j min_i d(i,j) ],  d = squared L2.
// d(i,j) = |p1_i|^2 + (|p2_j|^2 - 2 p1_i . p2_j); store min_j of the paren term.
//
// R3: scalar fp32 (R2 showed v_pk_fma_f32 does NOT raise FLOP rate on gfx950 —
// 157.3 TF spec = scalar SIMD-32 rate). Exact 2.5 instr/pair:
//   per pair: 2 v_fma_f32; per 2 pairs: 1 v_min3_f32 (asm, deterministic).
// j unrolled x4 with explicit LDS prefetch rotation (hide ~120cyc ds_read
// latency under 160 VALU instrs). S=32, IPT=16 -> 1024 blocks = 4 blocks/CU
// (16 waves/CU) with __launch_bounds__(256,4). d_out zeroed by block 0 of the
// partial kernel (saves the memset dispatch; reduce is stream-ordered after).

#define BATCH 8
#define NPTS  8192
#define TPB   256
#define IPT   16
#define PPB   (TPB * IPT)     // 4096
#define TILES (NPTS / PPB)    // 2

__device__ inline float min3f(float a, float b, float c) {
    float d;
    asm("v_min3_f32 %0, %1, %2, %3" : "=v"(d) : "v"(a), "v"(b), "v"(c));
    return d;
}

// grid.x = 2 * BATCH * TILES * S
template <int S>
__global__ __launch_bounds__(TPB, 4)
void chamfer_partial(const float* __restrict__ p1, const float* __restrict__ p2,
                     float* __restrict__ partial /* [2][B][S][N] */,
                     float* __restrict__ out_to_zero) {
    constexpr int JCH = NPTS / S;  // 256 at S=32
    __shared__ float4 q[JCH];      // (x, y, |p|^2, pad)

    if (blockIdx.x == 0 && threadIdx.x == 0) *out_to_zero = 0.0f;

    int blk   = blockIdx.x;
    int split = blk % S;            blk /= S;
    int tile  = blk & (TILES - 1);  blk >>= 1;
    int b     = blk & (BATCH - 1);  blk >>= 3;
    int dir   = blk;

    const float2* a  = (const float2*)(dir ? p2 : p1) + (size_t)b * NPTS;
    const float2* bp = (const float2*)(dir ? p1 : p2) + (size_t)b * NPTS + split * JCH;

    int t = threadIdx.x;

    for (int j = t; j < JCH; j += TPB) {
        float2 v = bp[j];
        q[j] = make_float4(v.x, v.y, fmaf(v.x, v.x, v.y * v.y), 0.0f);
    }

    int pt_base = tile * PPB;
    float xp[IPT], yp[IPT], m[IPT];
#pragma unroll
    for (int k = 0; k < IPT; ++k) {
        float2 v = a[pt_base + k * TPB + t];
        xp[k] = -2.0f * v.x;
        yp[k] = -2.0f * v.y;
        m[k]  = 3.0e38f;
    }

    __syncthreads();

    // software-pipelined: prefetch next 4 j's while computing current 4.
    float4 Q0 = q[0], Q1 = q[1], Q2 = q[2], Q3 = q[3];
    for (int j = 0; j < JCH - 4; j += 4) {
        float4 P0 = q[j + 4], P1 = q[j + 5], P2 = q[j + 6], P3 = q[j + 7];
#pragma unroll
        for (int k = 0; k < IPT; ++k) {
            float t0 = fmaf(yp[k], Q0.y, fmaf(xp[k], Q0.x, Q0.z));
            float t1 = fmaf(yp[k], Q1.y, fmaf(xp[k], Q1.x, Q1.z));
            float t2 = fmaf(yp[k], Q2.y, fmaf(xp[k], Q2.x, Q2.z));
            float t3 = fmaf(yp[k], Q3.y, fmaf(xp[k], Q3.x, Q3.z));
            m[k] = min3f(m[k], t0, t1);
            m[k] = min3f(m[k], t2, t3);
        }
        Q0 = P0; Q1 = P1; Q2 = P2; Q3 = P3;
    }
    // final group
#pragma unroll
    for (int k = 0; k < IPT; ++k) {
        float t0 = fmaf(yp[k], Q0.y, fmaf(xp[k], Q0.x, Q0.z));
        float t1 = fmaf(yp[k], Q1.y, fmaf(xp[k], Q1.x, Q1.z));
        float t2 = fmaf(yp[k], Q2.y, fmaf(xp[k], Q2.x, Q2.z));
        float t3 = fmaf(yp[k], Q3.y, fmaf(xp[k], Q3.x, Q3.z));
        m[k] = min3f(m[k], t0, t1);
        m[k] = min3f(m[k], t2, t3);
    }

    float* outp = partial + ((size_t)((dir * BATCH + b) * S + split)) * NPTS + pt_base;
#pragma unroll
    for (int k = 0; k < IPT; ++k)
        outp[k * TPB + t] = m[k];
}

// grid.x = 2 * BATCH * NPTS / TPB = 512
template <int S>
__global__ __launch_bounds__(TPB)
void chamfer_reduce(const float* __restrict__ p1, const float* __restrict__ p2,
                    const float* __restrict__ partial, float* __restrict__ out) {
    int gid   = blockIdx.x * TPB + threadIdx.x;
    int point = gid & (NPTS - 1);
    int rest  = gid >> 13;
    int b     = rest & (BATCH - 1);
    int dir   = rest >> 3;

    const float* base = partial + ((size_t)(dir * BATCH + b) * S) * NPTS + point;
    float m = base[0];
#pragma unroll
    for (int s = 1; s < S; ++s)
        m = fminf(m, base[(size_t)s * NPTS]);

    float2 v = ((const float2*)(dir ? p2 : p1))[(size_t)b * NPTS + point];
    float d = m + fmaf(v.x, v.x, v.y * v.y);

#pragma unroll
    for (int off = 32; off > 0; off >>= 1)
        d += __shfl_down(d, off, 64);

    __shared__ float wsum[TPB / 64];
    int lane = threadIdx.x & 63;
    int w    = threadIdx.x >> 6;
    if (lane == 0) wsum[w] = d;
    __syncthreads();
    if (threadIdx.x == 0) {
        float ssum = wsum[0] + wsum[1] + wsum[2] + wsum[3];
        atomicAdd(out, ssum * (1.0f / NPTS));
    }
}

extern "C" void kernel_launch(void* const* d_in, const int* in_sizes, int n_in,
                              void* d_out, int out_size, void* d_ws, size_t ws_size,
                              hipStream_t stream) {
    const float* p1 = (const float*)d_in[0];
    const float* p2 = (const float*)d_in[1];
    float* out      = (float*)d_out;
    float* partial  = (float*)d_ws;

    auto need = [](int S) { return (size_t)2 * BATCH * S * NPTS * sizeof(float); };

    if (ws_size >= need(32)) {
        chamfer_partial<32><<<2 * BATCH * TILES * 32, TPB, 0, stream>>>(p1, p2, partial, out);
        chamfer_reduce<32><<<2 * BATCH * NPTS / TPB, TPB, 0, stream>>>(p1, p2, partial, out);
    } else {
        chamfer_partial<16><<<2 * BATCH * TILES * 16, TPB, 0, stream>>>(p1, p2, partial, out);
        chamfer_reduce<16><<<2 * BATCH * NPTS / TPB, TPB, 0, stream>>>(p1, p2, partial, out);
    }
}